// Round 10
// baseline (202.619 us; speedup 1.0000x reference)
//
#include <hip/hip_runtime.h>
#include <hip/hip_bf16.h>

typedef __hip_bfloat16 bf16;

#define NPER 1024
#define CC   128
#define KK   64
#define NTOT 65536
#define ETOT 2097152
#define EPG  32768   // edges per graph
#define ESL  8192    // edges per sort slice (4 slices per graph)

// ---------------- workspace layout (bytes) ----
#define M_OFF    0            // bf16 [NTOT*KK] = 8,388,608
#define R_OFF    8388608      // bf16 [NTOT*KK] = 8,388,608  (root, then S in place)
#define SORT_OFF 16777216     // u16  [ETOT]    = 4,194,304  (LOCAL src ids, bucketed)
#define RP_OFF   20971520     // u16  [64*2048] =   262,144  (local inclusive ends)
#define FLAG_OFF 21233664     // int  [1]      (unused now, kept for layout stability)
#define ZB_OFF   21233728     // f32  [64]
#define WS_NEED  21233984ULL
#define WF_OFF   21233984     // u16  [2*4*4*64*8] = 32,768 (MFMA B-fragment packed W)
#define WS_NEED2 21266752ULL
// sort scratch ALIASED into m_buf (sort completes before mroot writes m):
#define GH_OFF   M_OFF              // int [256*2048] = 2 MB  (per-slice hists)
#define GC_OFF   (M_OFF + 2097152)  // int [256*2048] = 2 MB  (per-slice cursors)

typedef short bf16x8 __attribute__((ext_vector_type(8)));
typedef _Float16 half8 __attribute__((ext_vector_type(8)));
typedef float f32x4 __attribute__((ext_vector_type(4)));

// round-to-bf16 helper: matches the bf16-rounded expected values
__device__ __forceinline__ float t15_rb(float v) {
    return __bfloat162float(__float2bfloat16(v));
}
__device__ __forceinline__ float t15_bf(unsigned short h) {
    unsigned int w = ((unsigned int)h) << 16;
    float f;
    __builtin_memcpy(&f, &w, 4);
    return f;
}
__device__ __forceinline__ unsigned short t15_f2b(float f) {
    bf16 h = __float2bfloat16(f);
    unsigned short u;
    __builtin_memcpy(&u, &h, 2);
    return u;
}

__device__ __forceinline__ int t15_src(const int* ei, int e, int mode) {
    return (mode == 2 ? ei[2 * e] : ei[e]) & 65535;
}
__device__ __forceinline__ int t15_dst(const int* ei, int e, int mode) {
    return (mode == 2 ? ei[2 * ETOT + 2 * e] : ei[ETOT + e]) & 65535;
}

// ---- Sort phase 1: per-slice 2048-bucket histogram (256 blocks) ----
// key = (dst<<1)|(src>>9); slice = 8192 consecutive edges.
// Block 256 (extra) packs Wm/Wr into MFMA B-fragment order instead.
__global__ __launch_bounds__(1024) void t15_hist(const int* __restrict__ ei,
                                                 int* __restrict__ ghist,
                                                 const float* __restrict__ Wm,
                                                 const float* __restrict__ Wr,
                                                 unsigned short* __restrict__ wf) {
    int t = threadIdx.x;
    int blk = blockIdx.x;            // g*4 + q, or 256 = wprep
    if (blk == 256) {
        if (!wf) return;
        for (int idx = t; idx < 16384; idx += 1024) {
            int w = idx >> 13;
            int r = idx & 8191;
            int fr = r >> 3;
            int j = r & 7;
            int lane = fr & 63;
            int sc = fr >> 6;            // step*4 + ct
            int step = sc >> 2, ct = sc & 3;
            int c = step * 32 + 8 * (lane >> 4) + j;
            int kk = ct * 16 + (lane & 15);
            const float* W = w ? Wr : Wm;
            wf[idx] = t15_f2b(W[c * 64 + kk]);
        }
        return;
    }
    __shared__ int hist[2048];
    __shared__ int sdet[1024];
    __shared__ int smode;
    int ebase = blk * ESL;
    // local int32/int64 layout detect (OR of 1024 odd words of src range)
    sdet[t] = ei[2 * (ebase + t) + 1];
    __syncthreads();
    for (int off = 512; off; off >>= 1) {
        if (t < off) sdet[t] |= sdet[t + off];
        __syncthreads();
    }
    if (t == 0) smode = (sdet[0] != 0) ? 1 : 2;
    hist[t] = 0;
    hist[t + 1024] = 0;
    __syncthreads();
    int mode = smode;
    for (int i = t; i < ESL; i += 1024) {
        int e = ebase + i;
        int s = t15_src(ei, e, mode) & (NPER - 1);
        int d = t15_dst(ei, e, mode) & (NPER - 1);
        atomicAdd(&hist[(d << 1) | ((s >> 9) & 1)], 1);
    }
    __syncthreads();
    ghist[blk * 2048 + t] = hist[t];
    ghist[blk * 2048 + 1024 + t] = hist[t + 1024];
}

// ---- Sort phase 2: per-graph scan -> rowptr (u16 incl ends) + slice cursors ----
__global__ __launch_bounds__(1024) void t15_scan(const int* __restrict__ ghist,
                                                 int* __restrict__ gcur,
                                                 unsigned short* __restrict__ rowptr,
                                                 float* __restrict__ zbias) {
    __shared__ int sh[8192];      // 32 KB: 4 slice hists
    __shared__ int sscan[1024];
    int t = threadIdx.x, g = blockIdx.x;
    if (g == 0 && t < 64) zbias[t] = 0.f;
    for (int i = t; i < 8192; i += 1024) sh[i] = ghist[g * 8192 + i];
    __syncthreads();
    int b0 = 2 * t, b1 = 2 * t + 1;
    int h0[4], h1[4];
    int c0 = 0, c1 = 0;
#pragma unroll
    for (int q = 0; q < 4; ++q) {
        h0[q] = sh[q * 2048 + b0]; c0 += h0[q];
        h1[q] = sh[q * 2048 + b1]; c1 += h1[q];
    }
    int ts = c0 + c1;
    sscan[t] = ts;
    __syncthreads();
    for (int off = 1; off < 1024; off <<= 1) {
        int v = sscan[t];
        int a = (t >= off) ? sscan[t - off] : 0;
        __syncthreads();
        sscan[t] = v + a;
        __syncthreads();
    }
    int incl = sscan[t], excl = incl - ts;
    rowptr[g * 2048 + b0] = (unsigned short)(excl + c0);
    rowptr[g * 2048 + b1] = (unsigned short)incl;
    int r0 = excl, r1 = excl + c0;
#pragma unroll
    for (int q = 0; q < 4; ++q) {
        gcur[(g * 4 + q) * 2048 + b0] = r0; r0 += h0[q];
        gcur[(g * 4 + q) * 2048 + b1] = r1; r1 += h1[q];
    }
}

// ---- Sort phase 3: per-slice scatter using exact cursors (256 blocks) ----
__global__ __launch_bounds__(1024) void t15_scat(const int* __restrict__ ei,
                                                 const int* __restrict__ gcur,
                                                 unsigned short* __restrict__ sorted) {
    __shared__ int cur[2048];
    __shared__ int sdet[1024];
    __shared__ int smode;
    int t = threadIdx.x, blk = blockIdx.x;
    int ebase = blk * ESL;
    int g = blk >> 2;
    sdet[t] = ei[2 * (ebase + t) + 1];
    __syncthreads();
    for (int off = 512; off; off >>= 1) {
        if (t < off) sdet[t] |= sdet[t + off];
        __syncthreads();
    }
    if (t == 0) smode = (sdet[0] != 0) ? 1 : 2;
    cur[t] = gcur[blk * 2048 + t];
    cur[t + 1024] = gcur[blk * 2048 + 1024 + t];
    __syncthreads();
    int mode = smode;
    unsigned short* sg = sorted + g * EPG;
    for (int i = t; i < ESL; i += 1024) {
        int e = ebase + i;
        int s = t15_src(ei, e, mode) & (NPER - 1);
        int d = t15_dst(ei, e, mode) & (NPER - 1);
        int pos = atomicAdd(&cur[(d << 1) | ((s >> 9) & 1)], 1);
        if ((unsigned)pos < (unsigned)EPG) sg[pos] = (unsigned short)s;
    }
}

// ---- Stage 1 (MFMA): m = elu(x@Wm), root = x@Wr + b ----
__global__ __launch_bounds__(256) void t15_mroot_mfma(
        const float* __restrict__ x, const unsigned short* __restrict__ wf,
        const float* __restrict__ bias,
        bf16* __restrict__ m_out, bf16* __restrict__ root_out) {
    __shared__ unsigned short sX[64 * CC];   // 16 KB
    int t = threadIdx.x;
    int lane = t & 63;
    int wv = t >> 6;
    int ww = wv & 1;
    int ct0 = (wv >> 1) * 2;
    int rl = lane & 15, g2 = lane >> 4;

    bf16x8 bq[4][2];
    const uint4* wfq = (const uint4*)wf;
#pragma unroll
    for (int step = 0; step < 4; ++step)
#pragma unroll
        for (int cti = 0; cti < 2; ++cti) {
            uint4 u = wfq[(size_t)(((ww * 4 + step) * 4) + ct0 + cti) * 64 + lane];
            bq[step][cti] = __builtin_bit_cast(bf16x8, u);
        }
    float bv0 = bias[ct0 * 16 + rl];
    float bv1 = bias[ct0 * 16 + 16 + rl];
    bf16* dst = ww ? root_out : m_out;

    for (int ti = 0; ti < 2; ++ti) {
        int tile = blockIdx.x * 2 + ti;
        size_t rowbase = (size_t)tile * 64;
        if (ti) __syncthreads();
        // stage 64x128 fp32 -> bf16, swizzled
        const float4* xg = (const float4*)(x + rowbase * CC);
        for (int i = t; i < 2048; i += 256) {
            float4 v = xg[i];
            int row = i >> 5;
            int cb = (i & 31) * 8;                     // byte offset of 4 bf16
            int addr = row * 256 + (cb ^ ((row & 7) << 4));
            ushort4 h;
            h.x = t15_f2b(v.x); h.y = t15_f2b(v.y);
            h.z = t15_f2b(v.z); h.w = t15_f2b(v.w);
            *(ushort4*)((char*)sX + addr) = h;
        }
        __syncthreads();

        for (int rt = 0; rt < 4; ++rt) {
            int row = rt * 16 + rl;
            bf16x8 af[4];
#pragma unroll
            for (int step = 0; step < 4; ++step) {
                int addr = row * 256 + ((g2 * 16 + step * 64) ^ ((row & 7) << 4));
                uint4 u = *(const uint4*)((const char*)sX + addr);
                af[step] = __builtin_bit_cast(bf16x8, u);
            }
            f32x4 acc0 = {0.f, 0.f, 0.f, 0.f};
            f32x4 acc1 = {0.f, 0.f, 0.f, 0.f};
#pragma unroll
            for (int step = 0; step < 4; ++step) {
                acc0 = __builtin_amdgcn_mfma_f32_16x16x32_bf16(af[step], bq[step][0], acc0, 0, 0, 0);
                acc1 = __builtin_amdgcn_mfma_f32_16x16x32_bf16(af[step], bq[step][1], acc1, 0, 0, 0);
            }
            int n0 = (int)rowbase + rt * 16 + g2 * 4;
#pragma unroll
            for (int cti = 0; cti < 2; ++cti) {
                f32x4 a = cti ? acc1 : acc0;
                float bv = cti ? bv1 : bv0;
                int kk = (ct0 + cti) * 16 + rl;
#pragma unroll
                for (int r = 0; r < 4; ++r) {
                    float v = a[r];
                    if (ww) v += bv;
                    else    v = v > 0.f ? v : expm1f(v);
                    dst[(size_t)(n0 + r) * KK + kk] = __float2bfloat16(v);
                }
            }
        }
    }
}

// ---- Stage 1 fallback (scalar) — used only if workspace too small ----
__global__ void t15_mroot(const float* __restrict__ x, const float* __restrict__ Wm,
                          const float* __restrict__ Wr, const float* __restrict__ bias,
                          bf16* __restrict__ m_out, bf16* __restrict__ root_out) {
    __shared__ bf16 sWm[CC * KK];
    __shared__ bf16 sWr[CC * KK];
    __shared__ bf16 sX[64 * CC];
    int t = threadIdx.x;
    int nb = blockIdx.x * 64;
    for (int i = t; i < CC * KK; i += 256) {
        sWm[i] = __float2bfloat16(Wm[i]);
        sWr[i] = __float2bfloat16(Wr[i]);
    }
    const float4* xg = (const float4*)(x + (size_t)nb * CC);
    for (int i = t; i < (64 * CC) / 4; i += 256) {
        float4 v = xg[i];
        sX[i * 4 + 0] = __float2bfloat16(v.x);
        sX[i * 4 + 1] = __float2bfloat16(v.y);
        sX[i * 4 + 2] = __float2bfloat16(v.z);
        sX[i * 4 + 3] = __float2bfloat16(v.w);
    }
    int k = t & 63, rg = t >> 6;
    float bv = bias[k];
    __syncthreads();
    float accm[16], accr[16];
#pragma unroll
    for (int r = 0; r < 16; ++r) { accm[r] = 0.f; accr[r] = 0.f; }
    for (int c = 0; c < CC; ++c) {
        float wm = __bfloat162float(sWm[c * KK + k]);
        float wr = __bfloat162float(sWr[c * KK + k]);
#pragma unroll
        for (int r = 0; r < 16; ++r) {
            float xv = __bfloat162float(sX[(rg + 4 * r) * CC + c]);
            accm[r] += xv * wm;
            accr[r] += xv * wr;
        }
    }
#pragma unroll
    for (int r = 0; r < 16; ++r) {
        int n = nb + rg + 4 * r;
        float mv = accm[r];
        mv = mv > 0.f ? mv : expm1f(mv);
        m_out[(size_t)n * KK + k] = __float2bfloat16(mv);
        root_out[(size_t)n * KK + k] = __float2bfloat16(accr[r] + bv);
    }
}

// ---- Stage 3: LDS-staged PAIR-gather + tanh + softmax over K ----
// r10: one ds_read_b32 serves TWO edges: lanes 0-31 read edge e0's m-row as
// u32 k-pairs, lanes 32-63 read e1's row (2 lanes/bank = conflict-free).
// Each lane accumulates a k-pair (accL = even k, accH = odd k); lo-half
// lanes hold even-position edges, hi-half odd-position; a final
// shfl_xor(32) folds the halves. Softmax runs on 32 lanes x 2 components.
// DS ops per edge halved vs r7; register footprint stays ~80 VGPR.
__global__ __launch_bounds__(512, 4) void t15_gatherlds(
        const unsigned short* __restrict__ rowptr,
        const unsigned short* __restrict__ sorted_src,
        const unsigned short* __restrict__ m_in,
        bf16* __restrict__ rootS) {
    __shared__ unsigned short sM[512 * KK];   // 64 KB -> 2 blocks/CU
    const unsigned* sM32 = (const unsigned*)sM;
    int lane = threadIdx.x & 63;
    int wv = threadIdx.x >> 6;                // wave 0..7
    int g = blockIdx.x >> 3;                  // graph
    int nl0 = (blockIdx.x & 7) * 128 + wv * 16;  // local node base for this wave
    int nbase = g * NPER + nl0;
    const unsigned short* rp = rowptr + g * 2048;
    const unsigned short* idx = sorted_src + g * EPG;
    int b0 = 2 * nl0;
    int l31 = lane & 31;
    bool hi = lane >= 32;

    // lane L (0..32) holds local bucket boundary: (b0+L==0) ? 0 : rp[b0+L-1]
    unsigned rpv = 0;
    if (lane <= 32 && (b0 + lane) > 0) rpv = (unsigned)rp[b0 + lane - 1];

    float accL[16], accH[16];
    const unsigned* rS32 = (const unsigned*)rootS;
#pragma unroll
    for (int nn = 0; nn < 16; ++nn) {
        unsigned pr = rS32[(size_t)(nbase + nn) * 32 + l31];
        if (hi) pr = 0;     // root counted once (lo half only)
        accL[nn] = t15_bf((unsigned short)(pr & 0xffffu));
        accH[nn] = t15_bf((unsigned short)(pr >> 16));
    }

#pragma unroll
    for (int h = 0; h < 2; ++h) {
        // ---- issue all 16 segment index preloads (VMEM, pipelined) ----
        unsigned vi[16];
#pragma unroll
        for (int nn = 0; nn < 16; ++nn) {
            int bb = 2 * nn + h;
            int s = (int)__builtin_amdgcn_readlane(rpv, bb);
            int e = (int)__builtin_amdgcn_readlane(rpv, bb + 1);
            if (s > EPG) s = EPG;
            if (e < s) e = s;
            if (e > EPG) e = EPG;
            int w0 = s >> 1;
            int wc = ((e + 1) >> 1) - w0;
            if (wc > 64) wc = 64;
            unsigned v = 0;
            if (lane < wc) v = *(const unsigned*)(idx + 2 * (w0 + lane));
            vi[nn] = v;
        }
        // ---- stage m half into LDS (hides the preload latency) ----
        if (h) __syncthreads();   // all waves done reading previous half
        const uint4* mg = (const uint4*)(m_in + ((size_t)g * NPER + h * 512) * KK);
        uint4* ml = (uint4*)sM;
        for (int i = threadIdx.x; i < (512 * KK) / 8; i += 512) ml[i] = mg[i];
        __syncthreads();

        // ---- process segments: 1 ds_read_b32 per 2 edges ----
#pragma unroll
        for (int nn = 0; nn < 16; ++nn) {
            int bb = 2 * nn + h;
            int s = (int)__builtin_amdgcn_readlane(rpv, bb);
            int e = (int)__builtin_amdgcn_readlane(rpv, bb + 1);
            if (s > EPG) s = EPG;
            if (e < s) e = s;
            if (e > EPG) e = EPG;
            int w0 = s >> 1;
            int wc = ((e + 1) >> 1) - w0;
            if (wc > 64) wc = 64;
            int elim = 2 * (w0 + wc);
            if (elim > e) elim = e;
            float aL = accL[nn], aH = accH[nn];
            int j = 0;
            if ((s & 1) && s < elim) {        // odd start: single edge, hi u16 of word 0
                unsigned w = __builtin_amdgcn_readlane(vi[nn], 0);
                unsigned v = sM32[((w >> 16) & 511u) * 32 + l31];
                if (hi) v = 0;                // count once
                aL += t15_bf((unsigned short)(v & 0xffffu));
                aH += t15_bf((unsigned short)(v >> 16));
                j = 1;
            }
            int jfull = (elim >> 1) - w0;     // # complete 2-edge words
            for (; j < jfull; ++j) {
                unsigned w = __builtin_amdgcn_readlane(vi[nn], j);
                unsigned s0 = w & 511u;
                unsigned s1 = (w >> 16) & 511u;
                unsigned sel = hi ? s1 : s0;
                unsigned v = sM32[sel * 32 + l31];
                aL += t15_bf((unsigned short)(v & 0xffffu));
                aH += t15_bf((unsigned short)(v >> 16));
            }
            if ((elim & 1) && elim > s) {     // odd tail: lo u16 of word jfull
                unsigned w = __builtin_amdgcn_readlane(vi[nn], jfull);
                unsigned v = sM32[(w & 511u) * 32 + l31];
                if (hi) v = 0;
                aL += t15_bf((unsigned short)(v & 0xffffu));
                aH += t15_bf((unsigned short)(v >> 16));
            }
            for (int i = elim; i < e; ++i) {  // ultra-rare: segment > 128 edges
                unsigned sv = __builtin_amdgcn_readfirstlane((unsigned)idx[i]);
                unsigned v = sM32[(sv & 511u) * 32 + l31];
                if (hi) v = 0;
                aL += t15_bf((unsigned short)(v & 0xffffu));
                aH += t15_bf((unsigned short)(v >> 16));
            }
            accL[nn] = aL; accH[nn] = aH;
        }
    }

#pragma unroll
    for (int nn = 0; nn < 16; ++nn) {
        float aL = accL[nn] + __shfl_xor(accL[nn], 32, 64);   // evens + odds
        float aH = accH[nn] + __shfl_xor(accH[nn], 32, 64);
        float svL = tanhf(aL), svH = tanhf(aH);
        float mx = fmaxf(svL, svH);
        for (int o = 16; o; o >>= 1) mx = fmaxf(mx, __shfl_xor(mx, o, 64));
        float eL = expf(svL - mx), eH = expf(svH - mx);
        float sm = eL + eH;
        for (int o = 16; o; o >>= 1) sm += __shfl_xor(sm, o, 64);
        unsigned outw = (unsigned)t15_f2b(eL / sm) | ((unsigned)t15_f2b(eH / sm) << 16);
        if (lane < 32)
            ((unsigned*)rootS)[(size_t)(nbase + nn) * 32 + l31] = outw;
    }
}

// ---- Stage 4 (MFMA, fp16) + fused edgefill tail blocks ----
// Blocks 0..255: out[g*64+k, c] = sum_n S[g,n,k]*X[g,n,c] (as r9).
// Blocks 256..1287: edge_index_out + batch_out fill (fused former launch).
__global__ __launch_bounds__(512) void t15_pool_mfma(
        const float* __restrict__ x, const bf16* __restrict__ S_in,
        float* __restrict__ outp) {
    __shared__ char sP[24576];     // St: [64][256B] @0 ; Xt: [32][256B] @16384
    int tt = threadIdx.x;
    if (blockIdx.x >= 256) {
        int gid = (blockIdx.x - 256) * 512 + tt;
        if (gid >= 528384) return;
        float val;
        if (gid < 524288) {
            int r = gid >> 18;        // row 0/1 of edge_index_out
            int rem = gid & 262143;
            int b = rem >> 12;        // graph
            int p = rem & 4095;       // pair index within graph
            int v = (r == 0) ? (p >> 6) : (p & 63);
            val = (float)(v + b * 64);
        } else {
            val = (float)((gid - 524288) >> 6);   // batch_out
        }
        outp[524288 + gid] = t15_rb(val);
        return;
    }
    int lane = tt & 63;
    int wv = tt >> 6;              // 0..7
    int mt = wv & 3;               // k-tile
    int nt = wv >> 2;              // c-tile within quarter
    int rl = lane & 15, g2 = lane >> 4;
    int g = blockIdx.x >> 2;
    int cq = (blockIdx.x & 3) * 32;

    f32x4 acc = {0.f, 0.f, 0.f, 0.f};

    for (int tile = 0; tile < 8; ++tile) {
        size_t nbase = (size_t)g * NPER + tile * 128;
        if (tile) __syncthreads();
        // ---- stage S[128n][64k] bf16 -> St[64k][128n] fp16 (swizzled) ----
        const uint2* sg = (const uint2*)(S_in + nbase * KK);
        for (int i = 0; i < 4; ++i) {
            int idx = tt + 512 * i;          // 0..2047
            int r = idx >> 4;                // n
            int q = idx & 15;                // k quad
            uint2 u = sg[idx];
            unsigned short b[4] = {(unsigned short)(u.x & 0xffff),
                                   (unsigned short)(u.x >> 16),
                                   (unsigned short)(u.y & 0xffff),
                                   (unsigned short)(u.y >> 16)};
#pragma unroll
            for (int j = 0; j < 4; ++j) {
                int k = 4 * q + j;
                _Float16 h = (_Float16)t15_bf(b[j]);
                *(_Float16*)(sP + k * 256 + ((2 * r) ^ ((k & 7) << 4))) = h;
            }
        }
        // ---- stage X[128n][32c] f32 -> Xt[32c][128n] fp16 (swizzled) ----
        const float* xb = x + nbase * CC + cq;
        for (int i = 0; i < 2; ++i) {
            int idx = tt + 512 * i;          // 0..1023
            int r = idx >> 3;                // n
            int q = idx & 7;                 // c quad
            float4 v = *(const float4*)(xb + (size_t)r * CC + 4 * q);
#pragma unroll
            for (int j = 0; j < 4; ++j) {
                int c = 4 * q + j;
                float fv = (j == 0) ? v.x : (j == 1) ? v.y : (j == 2) ? v.z : v.w;
                _Float16 h = (_Float16)fv;
                *(_Float16*)(sP + 16384 + c * 256 + ((2 * r) ^ ((c & 7) << 4))) = h;
            }
        }
        __syncthreads();
        // ---- 4 K-steps of 32 n ----
#pragma unroll
        for (int ks = 0; ks < 4; ++ks) {
            int nb2 = 2 * (32 * ks + 8 * g2);          // byte offset of n-chunk
            int arow = 16 * mt + rl;
            uint4 ua = *(const uint4*)(sP + arow * 256 + (nb2 ^ ((arow & 7) << 4)));
            int brow = 16 * nt + rl;
            uint4 ub = *(const uint4*)(sP + 16384 + brow * 256 + (nb2 ^ ((brow & 7) << 4)));
            half8 A = __builtin_bit_cast(half8, ua);
            half8 B = __builtin_bit_cast(half8, ub);
            acc = __builtin_amdgcn_mfma_f32_16x16x32_f16(A, B, acc, 0, 0, 0);
        }
    }

    // ---- epilogue: C row = 4*g2 + reg (k within mt), col = rl (c within nt) ----
#pragma unroll
    for (int r = 0; r < 4; ++r) {
        int krow = 16 * mt + 4 * g2 + r;
        outp[(size_t)(g * KK + krow) * CC + cq + 16 * nt + rl] = t15_rb(acc[r]);
    }
}

// ---- Stage 5 (fallback only): edge_index_out + batch_out ----
__global__ void t15_edgefill(float* __restrict__ outp) {
    int gid = blockIdx.x * 256 + threadIdx.x;
    if (gid >= 528384) return;
    float val;
    if (gid < 524288) {
        int r = gid >> 18;        // row 0/1 of edge_index_out
        int rem = gid & 262143;
        int b = rem >> 12;        // graph
        int p = rem & 4095;       // pair index within graph
        int v = (r == 0) ? (p >> 6) : (p & 63);
        val = (float)(v + b * 64);
    } else {
        val = (float)((gid - 524288) >> 6);   // batch_out
    }
    outp[524288 + gid] = t15_rb(val);
}

extern "C" void kernel_launch(void* const* d_in, const int* in_sizes, int n_in,
                              void* d_out, int out_size, void* d_ws, size_t ws_size,
                              hipStream_t stream) {
    const float* x = nullptr; const int* ei = nullptr;
    const float* Wm = nullptr; const float* Wr = nullptr; const float* bias = nullptr;
    for (int i = 0; i < n_in; ++i) {
        int s = in_sizes[i];
        if (s == 8388608 && !x)       x  = (const float*)d_in[i];
        else if (s == 4194304 && !ei) ei = (const int*)d_in[i];
        else if (s == 8192) { if (!Wm) Wm = (const float*)d_in[i]; else if (!Wr) Wr = (const float*)d_in[i]; }
        else if (s == 64 && !bias)    bias = (const float*)d_in[i];
    }
    if (!x)  x  = (const float*)d_in[0];
    if (!ei) ei = (const int*)d_in[1];
    if (!Wm && n_in > 3) Wm = (const float*)d_in[3];
    if (!Wr && n_in > 4) Wr = (const float*)d_in[4];

    float* outp = (float*)d_out;           // d_out is FLOAT32
    bool out_ok = (out_size >= 1052672);
    bool ws_ok  = (ws_size >= WS_NEED) && x && ei && Wm && Wr;
    bool wf_ok  = (ws_size >= WS_NEED2);

    if (out_ok && !ws_ok) {
        t15_edgefill<<<2064, 256, 0, stream>>>(outp);
    }
    if (out_ok && ws_ok) {
        char* ws = (char*)d_ws;
        bf16*           m_buf  = (bf16*)(ws + M_OFF);
        bf16*           rootS  = (bf16*)(ws + R_OFF);
        unsigned short* sorted = (unsigned short*)(ws + SORT_OFF);
        unsigned short* rowptr = (unsigned short*)(ws + RP_OFF);
        float*          zbias  = (float*)(ws + ZB_OFF);
        unsigned short* wf     = wf_ok ? (unsigned short*)(ws + WF_OFF) : nullptr;
        int*            ghist  = (int*)(ws + GH_OFF);   // aliases m_buf (pre-mroot)
        int*            gcur   = (int*)(ws + GC_OFF);   // aliases m_buf (pre-mroot)
        const float* bz = bias ? bias : zbias;

        t15_hist<<<257, 1024, 0, stream>>>(ei, ghist, Wm, Wr, wf);
        t15_scan<<<64, 1024, 0, stream>>>(ghist, gcur, rowptr, zbias);
        t15_scat<<<256, 1024, 0, stream>>>(ei, gcur, sorted);
        if (wf_ok)
            t15_mroot_mfma<<<512, 256, 0, stream>>>(x, wf, bz, m_buf, rootS);
        else
            t15_mroot<<<NTOT / 64, 256, 0, stream>>>(x, Wm, Wr, bz, m_buf, rootS);
        t15_gatherlds<<<512, 512, 0, stream>>>(rowptr, sorted,
                                               (const unsigned short*)m_buf, rootS);
        t15_pool_mfma<<<1288, 512, 0, stream>>>(x, rootS, outp);
    }
}

// Round 11
// 192.011 us; speedup vs baseline: 1.0553x; 1.0553x over previous
//
#include <hip/hip_runtime.h>
#include <hip/hip_bf16.h>

typedef __hip_bfloat16 bf16;

#define NPER 1024
#define CC   128
#define KK   64
#define NTOT 65536
#define ETOT 2097152
#define EPG  32768   // edges per graph
#define ESL  8192    // edges per sort slice (4 slices per graph)

// ---------------- workspace layout (bytes) ----
#define M_OFF    0            // bf16 [NTOT*KK] = 8,388,608
#define R_OFF    8388608      // bf16 [NTOT*KK] = 8,388,608  (root, then S in place)
#define SORT_OFF 16777216     // u16  [ETOT]    = 4,194,304  (LOCAL src ids, bucketed)
#define RP_OFF   20971520     // u16  [64*2048] =   262,144  (local inclusive ends)
#define FLAG_OFF 21233664     // int  [1]      (unused now, kept for layout stability)
#define ZB_OFF   21233728     // f32  [64]
#define WS_NEED  21233984ULL
#define WF_OFF   21233984     // u16  [2*4*4*64*8] = 32,768 (MFMA B-fragment packed W)
#define WS_NEED2 21266752ULL
// sort scratch ALIASED into m_buf (sort completes before mroot writes m):
#define GH_OFF   M_OFF              // int [256*2048] = 2 MB  (per-slice hists)
#define GC_OFF   (M_OFF + 2097152)  // int [256*2048] = 2 MB  (per-slice cursors)

typedef short bf16x8 __attribute__((ext_vector_type(8)));
typedef _Float16 half8 __attribute__((ext_vector_type(8)));
typedef float f32x4 __attribute__((ext_vector_type(4)));

// round-to-bf16 helper: matches the bf16-rounded expected values
__device__ __forceinline__ float t15_rb(float v) {
    return __bfloat162float(__float2bfloat16(v));
}
__device__ __forceinline__ float t15_bf(unsigned short h) {
    unsigned int w = ((unsigned int)h) << 16;
    float f;
    __builtin_memcpy(&f, &w, 4);
    return f;
}
__device__ __forceinline__ unsigned short t15_f2b(float f) {
    bf16 h = __float2bfloat16(f);
    unsigned short u;
    __builtin_memcpy(&u, &h, 2);
    return u;
}

__device__ __forceinline__ int t15_src(const int* ei, int e, int mode) {
    return (mode == 2 ? ei[2 * e] : ei[e]) & 65535;
}
__device__ __forceinline__ int t15_dst(const int* ei, int e, int mode) {
    return (mode == 2 ? ei[2 * ETOT + 2 * e] : ei[ETOT + e]) & 65535;
}

// ---- Sort phase 1: per-slice 2048-bucket histogram (256 blocks) ----
// key = (dst<<1)|(src>>9); slice = 8192 consecutive edges.
// Block 256 (extra) packs Wm/Wr into MFMA B-fragment order instead.
__global__ __launch_bounds__(1024) void t15_hist(const int* __restrict__ ei,
                                                 int* __restrict__ ghist,
                                                 const float* __restrict__ Wm,
                                                 const float* __restrict__ Wr,
                                                 unsigned short* __restrict__ wf) {
    int t = threadIdx.x;
    int blk = blockIdx.x;            // g*4 + q, or 256 = wprep
    if (blk == 256) {
        if (!wf) return;
        for (int idx = t; idx < 16384; idx += 1024) {
            int w = idx >> 13;
            int r = idx & 8191;
            int fr = r >> 3;
            int j = r & 7;
            int lane = fr & 63;
            int sc = fr >> 6;            // step*4 + ct
            int step = sc >> 2, ct = sc & 3;
            int c = step * 32 + 8 * (lane >> 4) + j;
            int kk = ct * 16 + (lane & 15);
            const float* W = w ? Wr : Wm;
            wf[idx] = t15_f2b(W[c * 64 + kk]);
        }
        return;
    }
    __shared__ int hist[2048];
    __shared__ int sdet[1024];
    __shared__ int smode;
    int ebase = blk * ESL;
    // local int32/int64 layout detect (OR of 1024 odd words of src range)
    sdet[t] = ei[2 * (ebase + t) + 1];
    __syncthreads();
    for (int off = 512; off; off >>= 1) {
        if (t < off) sdet[t] |= sdet[t + off];
        __syncthreads();
    }
    if (t == 0) smode = (sdet[0] != 0) ? 1 : 2;
    hist[t] = 0;
    hist[t + 1024] = 0;
    __syncthreads();
    int mode = smode;
    for (int i = t; i < ESL; i += 1024) {
        int e = ebase + i;
        int s = t15_src(ei, e, mode) & (NPER - 1);
        int d = t15_dst(ei, e, mode) & (NPER - 1);
        atomicAdd(&hist[(d << 1) | ((s >> 9) & 1)], 1);
    }
    __syncthreads();
    ghist[blk * 2048 + t] = hist[t];
    ghist[blk * 2048 + 1024 + t] = hist[t + 1024];
}

// ---- Sort phase 2: per-graph scan -> rowptr (u16 incl ends) + slice cursors ----
__global__ __launch_bounds__(1024) void t15_scan(const int* __restrict__ ghist,
                                                 int* __restrict__ gcur,
                                                 unsigned short* __restrict__ rowptr,
                                                 float* __restrict__ zbias) {
    __shared__ int sh[8192];      // 32 KB: 4 slice hists
    __shared__ int sscan[1024];
    int t = threadIdx.x, g = blockIdx.x;
    if (g == 0 && t < 64) zbias[t] = 0.f;
    for (int i = t; i < 8192; i += 1024) sh[i] = ghist[g * 8192 + i];
    __syncthreads();
    int b0 = 2 * t, b1 = 2 * t + 1;
    int h0[4], h1[4];
    int c0 = 0, c1 = 0;
#pragma unroll
    for (int q = 0; q < 4; ++q) {
        h0[q] = sh[q * 2048 + b0]; c0 += h0[q];
        h1[q] = sh[q * 2048 + b1]; c1 += h1[q];
    }
    int ts = c0 + c1;
    sscan[t] = ts;
    __syncthreads();
    for (int off = 1; off < 1024; off <<= 1) {
        int v = sscan[t];
        int a = (t >= off) ? sscan[t - off] : 0;
        __syncthreads();
        sscan[t] = v + a;
        __syncthreads();
    }
    int incl = sscan[t], excl = incl - ts;
    rowptr[g * 2048 + b0] = (unsigned short)(excl + c0);
    rowptr[g * 2048 + b1] = (unsigned short)incl;
    int r0 = excl, r1 = excl + c0;
#pragma unroll
    for (int q = 0; q < 4; ++q) {
        gcur[(g * 4 + q) * 2048 + b0] = r0; r0 += h0[q];
        gcur[(g * 4 + q) * 2048 + b1] = r1; r1 += h1[q];
    }
}

// ---- Sort phase 3: per-slice scatter using exact cursors (256 blocks) ----
__global__ __launch_bounds__(1024) void t15_scat(const int* __restrict__ ei,
                                                 const int* __restrict__ gcur,
                                                 unsigned short* __restrict__ sorted) {
    __shared__ int cur[2048];
    __shared__ int sdet[1024];
    __shared__ int smode;
    int t = threadIdx.x, blk = blockIdx.x;
    int ebase = blk * ESL;
    int g = blk >> 2;
    sdet[t] = ei[2 * (ebase + t) + 1];
    __syncthreads();
    for (int off = 512; off; off >>= 1) {
        if (t < off) sdet[t] |= sdet[t + off];
        __syncthreads();
    }
    if (t == 0) smode = (sdet[0] != 0) ? 1 : 2;
    cur[t] = gcur[blk * 2048 + t];
    cur[t + 1024] = gcur[blk * 2048 + 1024 + t];
    __syncthreads();
    int mode = smode;
    unsigned short* sg = sorted + g * EPG;
    for (int i = t; i < ESL; i += 1024) {
        int e = ebase + i;
        int s = t15_src(ei, e, mode) & (NPER - 1);
        int d = t15_dst(ei, e, mode) & (NPER - 1);
        int pos = atomicAdd(&cur[(d << 1) | ((s >> 9) & 1)], 1);
        if ((unsigned)pos < (unsigned)EPG) sg[pos] = (unsigned short)s;
    }
}

// ---- Stage 1 (MFMA): m = elu(x@Wm), root = x@Wr + b ----
__global__ __launch_bounds__(256) void t15_mroot_mfma(
        const float* __restrict__ x, const unsigned short* __restrict__ wf,
        const float* __restrict__ bias,
        bf16* __restrict__ m_out, bf16* __restrict__ root_out) {
    __shared__ unsigned short sX[64 * CC];   // 16 KB
    int t = threadIdx.x;
    int lane = t & 63;
    int wv = t >> 6;
    int ww = wv & 1;
    int ct0 = (wv >> 1) * 2;
    int rl = lane & 15, g2 = lane >> 4;

    bf16x8 bq[4][2];
    const uint4* wfq = (const uint4*)wf;
#pragma unroll
    for (int step = 0; step < 4; ++step)
#pragma unroll
        for (int cti = 0; cti < 2; ++cti) {
            uint4 u = wfq[(size_t)(((ww * 4 + step) * 4) + ct0 + cti) * 64 + lane];
            bq[step][cti] = __builtin_bit_cast(bf16x8, u);
        }
    float bv0 = bias[ct0 * 16 + rl];
    float bv1 = bias[ct0 * 16 + 16 + rl];
    bf16* dst = ww ? root_out : m_out;

    for (int ti = 0; ti < 2; ++ti) {
        int tile = blockIdx.x * 2 + ti;
        size_t rowbase = (size_t)tile * 64;
        if (ti) __syncthreads();
        // stage 64x128 fp32 -> bf16, swizzled
        const float4* xg = (const float4*)(x + rowbase * CC);
        for (int i = t; i < 2048; i += 256) {
            float4 v = xg[i];
            int row = i >> 5;
            int cb = (i & 31) * 8;                     // byte offset of 4 bf16
            int addr = row * 256 + (cb ^ ((row & 7) << 4));
            ushort4 h;
            h.x = t15_f2b(v.x); h.y = t15_f2b(v.y);
            h.z = t15_f2b(v.z); h.w = t15_f2b(v.w);
            *(ushort4*)((char*)sX + addr) = h;
        }
        __syncthreads();

        for (int rt = 0; rt < 4; ++rt) {
            int row = rt * 16 + rl;
            bf16x8 af[4];
#pragma unroll
            for (int step = 0; step < 4; ++step) {
                int addr = row * 256 + ((g2 * 16 + step * 64) ^ ((row & 7) << 4));
                uint4 u = *(const uint4*)((const char*)sX + addr);
                af[step] = __builtin_bit_cast(bf16x8, u);
            }
            f32x4 acc0 = {0.f, 0.f, 0.f, 0.f};
            f32x4 acc1 = {0.f, 0.f, 0.f, 0.f};
#pragma unroll
            for (int step = 0; step < 4; ++step) {
                acc0 = __builtin_amdgcn_mfma_f32_16x16x32_bf16(af[step], bq[step][0], acc0, 0, 0, 0);
                acc1 = __builtin_amdgcn_mfma_f32_16x16x32_bf16(af[step], bq[step][1], acc1, 0, 0, 0);
            }
            int n0 = (int)rowbase + rt * 16 + g2 * 4;
#pragma unroll
            for (int cti = 0; cti < 2; ++cti) {
                f32x4 a = cti ? acc1 : acc0;
                float bv = cti ? bv1 : bv0;
                int kk = (ct0 + cti) * 16 + rl;
#pragma unroll
                for (int r = 0; r < 4; ++r) {
                    float v = a[r];
                    if (ww) v += bv;
                    else    v = v > 0.f ? v : expm1f(v);
                    dst[(size_t)(n0 + r) * KK + kk] = __float2bfloat16(v);
                }
            }
        }
    }
}

// ---- Stage 1 fallback (scalar) — used only if workspace too small ----
__global__ void t15_mroot(const float* __restrict__ x, const float* __restrict__ Wm,
                          const float* __restrict__ Wr, const float* __restrict__ bias,
                          bf16* __restrict__ m_out, bf16* __restrict__ root_out) {
    __shared__ bf16 sWm[CC * KK];
    __shared__ bf16 sWr[CC * KK];
    __shared__ bf16 sX[64 * CC];
    int t = threadIdx.x;
    int nb = blockIdx.x * 64;
    for (int i = t; i < CC * KK; i += 256) {
        sWm[i] = __float2bfloat16(Wm[i]);
        sWr[i] = __float2bfloat16(Wr[i]);
    }
    const float4* xg = (const float4*)(x + (size_t)nb * CC);
    for (int i = t; i < (64 * CC) / 4; i += 256) {
        float4 v = xg[i];
        sX[i * 4 + 0] = __float2bfloat16(v.x);
        sX[i * 4 + 1] = __float2bfloat16(v.y);
        sX[i * 4 + 2] = __float2bfloat16(v.z);
        sX[i * 4 + 3] = __float2bfloat16(v.w);
    }
    int k = t & 63, rg = t >> 6;
    float bv = bias[k];
    __syncthreads();
    float accm[16], accr[16];
#pragma unroll
    for (int r = 0; r < 16; ++r) { accm[r] = 0.f; accr[r] = 0.f; }
    for (int c = 0; c < CC; ++c) {
        float wm = __bfloat162float(sWm[c * KK + k]);
        float wr = __bfloat162float(sWr[c * KK + k]);
#pragma unroll
        for (int r = 0; r < 16; ++r) {
            float xv = __bfloat162float(sX[(rg + 4 * r) * CC + c]);
            accm[r] += xv * wm;
            accr[r] += xv * wr;
        }
    }
#pragma unroll
    for (int r = 0; r < 16; ++r) {
        int n = nb + rg + 4 * r;
        float mv = accm[r];
        mv = mv > 0.f ? mv : expm1f(mv);
        m_out[(size_t)n * KK + k] = __float2bfloat16(mv);
        root_out[(size_t)n * KK + k] = __float2bfloat16(accr[r] + bv);
    }
}

// ---- Stage 3: LDS-staged PAIR-gather + tanh + softmax over K ----
// r11: 1024-thread blocks (16 waves, 8 nodes/wave). 64 KB LDS/block ->
// 2 blocks/CU = 128 KB <= 160 KB -> 32 waves/CU (was 16): doubles TLP on a
// kernel whose VALU (55%) and DS (~40%) pipes were both half-idle.
// Pair-gather as r10: one ds_read_b32 serves two edges (lanes 0-31 = even
// edge, 32-63 = odd edge); per-lane k-pair accumulators; shfl_xor(32) fold.
__global__ __launch_bounds__(1024, 8) void t15_gatherlds(
        const unsigned short* __restrict__ rowptr,
        const unsigned short* __restrict__ sorted_src,
        const unsigned short* __restrict__ m_in,
        bf16* __restrict__ rootS) {
    __shared__ unsigned short sM[512 * KK];   // 64 KB -> 2 blocks/CU
    const unsigned* sM32 = (const unsigned*)sM;
    int lane = threadIdx.x & 63;
    int wv = threadIdx.x >> 6;                // wave 0..15
    int g = blockIdx.x >> 3;                  // graph
    int nl0 = (blockIdx.x & 7) * 128 + wv * 8;   // local node base for this wave
    int nbase = g * NPER + nl0;
    const unsigned short* rp = rowptr + g * 2048;
    const unsigned short* idx = sorted_src + g * EPG;
    int b0 = 2 * nl0;
    int l31 = lane & 31;
    bool hi = lane >= 32;

    // lane L (0..16) holds local bucket boundary: (b0+L==0) ? 0 : rp[b0+L-1]
    unsigned rpv = 0;
    if (lane <= 16 && (b0 + lane) > 0) rpv = (unsigned)rp[b0 + lane - 1];

    float accL[8], accH[8];
    const unsigned* rS32 = (const unsigned*)rootS;
#pragma unroll
    for (int nn = 0; nn < 8; ++nn) {
        unsigned pr = rS32[(size_t)(nbase + nn) * 32 + l31];
        if (hi) pr = 0;     // root counted once (lo half only)
        accL[nn] = t15_bf((unsigned short)(pr & 0xffffu));
        accH[nn] = t15_bf((unsigned short)(pr >> 16));
    }

#pragma unroll
    for (int h = 0; h < 2; ++h) {
        // ---- issue all 8 segment index preloads (VMEM, pipelined) ----
        unsigned vi[8];
#pragma unroll
        for (int nn = 0; nn < 8; ++nn) {
            int bb = 2 * nn + h;
            int s = (int)__builtin_amdgcn_readlane(rpv, bb);
            int e = (int)__builtin_amdgcn_readlane(rpv, bb + 1);
            if (s > EPG) s = EPG;
            if (e < s) e = s;
            if (e > EPG) e = EPG;
            int w0 = s >> 1;
            int wc = ((e + 1) >> 1) - w0;
            if (wc > 64) wc = 64;
            unsigned v = 0;
            if (lane < wc) v = *(const unsigned*)(idx + 2 * (w0 + lane));
            vi[nn] = v;
        }
        // ---- stage m half into LDS (hides the preload latency) ----
        if (h) __syncthreads();   // all waves done reading previous half
        const uint4* mg = (const uint4*)(m_in + ((size_t)g * NPER + h * 512) * KK);
        uint4* ml = (uint4*)sM;
        for (int i = threadIdx.x; i < (512 * KK) / 8; i += 1024) ml[i] = mg[i];
        __syncthreads();

        // ---- process segments: 1 ds_read_b32 per 2 edges ----
#pragma unroll
        for (int nn = 0; nn < 8; ++nn) {
            int bb = 2 * nn + h;
            int s = (int)__builtin_amdgcn_readlane(rpv, bb);
            int e = (int)__builtin_amdgcn_readlane(rpv, bb + 1);
            if (s > EPG) s = EPG;
            if (e < s) e = s;
            if (e > EPG) e = EPG;
            int w0 = s >> 1;
            int wc = ((e + 1) >> 1) - w0;
            if (wc > 64) wc = 64;
            int elim = 2 * (w0 + wc);
            if (elim > e) elim = e;
            float aL = accL[nn], aH = accH[nn];
            int j = 0;
            if ((s & 1) && s < elim) {        // odd start: single edge, hi u16 of word 0
                unsigned w = __builtin_amdgcn_readlane(vi[nn], 0);
                unsigned v = sM32[((w >> 16) & 511u) * 32 + l31];
                if (hi) v = 0;                // count once
                aL += t15_bf((unsigned short)(v & 0xffffu));
                aH += t15_bf((unsigned short)(v >> 16));
                j = 1;
            }
            int jfull = (elim >> 1) - w0;     // # complete 2-edge words
            for (; j < jfull; ++j) {
                unsigned w = __builtin_amdgcn_readlane(vi[nn], j);
                unsigned s0 = w & 511u;
                unsigned s1 = (w >> 16) & 511u;
                unsigned sel = hi ? s1 : s0;
                unsigned v = sM32[sel * 32 + l31];
                aL += t15_bf((unsigned short)(v & 0xffffu));
                aH += t15_bf((unsigned short)(v >> 16));
            }
            if ((elim & 1) && elim > s) {     // odd tail: lo u16 of word jfull
                unsigned w = __builtin_amdgcn_readlane(vi[nn], jfull);
                unsigned v = sM32[(w & 511u) * 32 + l31];
                if (hi) v = 0;
                aL += t15_bf((unsigned short)(v & 0xffffu));
                aH += t15_bf((unsigned short)(v >> 16));
            }
            for (int i = elim; i < e; ++i) {  // ultra-rare: segment > 128 edges
                unsigned sv = __builtin_amdgcn_readfirstlane((unsigned)idx[i]);
                unsigned v = sM32[(sv & 511u) * 32 + l31];
                if (hi) v = 0;
                aL += t15_bf((unsigned short)(v & 0xffffu));
                aH += t15_bf((unsigned short)(v >> 16));
            }
            accL[nn] = aL; accH[nn] = aH;
        }
    }

#pragma unroll
    for (int nn = 0; nn < 8; ++nn) {
        float aL = accL[nn] + __shfl_xor(accL[nn], 32, 64);   // evens + odds
        float aH = accH[nn] + __shfl_xor(accH[nn], 32, 64);
        float svL = tanhf(aL), svH = tanhf(aH);
        float mx = fmaxf(svL, svH);
        for (int o = 16; o; o >>= 1) mx = fmaxf(mx, __shfl_xor(mx, o, 64));
        float eL = expf(svL - mx), eH = expf(svH - mx);
        float sm = eL + eH;
        for (int o = 16; o; o >>= 1) sm += __shfl_xor(sm, o, 64);
        unsigned outw = (unsigned)t15_f2b(eL / sm) | ((unsigned)t15_f2b(eH / sm) << 16);
        if (lane < 32)
            ((unsigned*)rootS)[(size_t)(nbase + nn) * 32 + l31] = outw;
    }
}

// ---- Stage 4 (MFMA, fp16) + fused edgefill tail blocks ----
// Blocks 0..255: out[g*64+k, c] = sum_n S[g,n,k]*X[g,n,c].
// Blocks 256..1287: edge_index_out + batch_out fill.
__global__ __launch_bounds__(512) void t15_pool_mfma(
        const float* __restrict__ x, const bf16* __restrict__ S_in,
        float* __restrict__ outp) {
    __shared__ char sP[24576];     // St: [64][256B] @0 ; Xt: [32][256B] @16384
    int tt = threadIdx.x;
    if (blockIdx.x >= 256) {
        int gid = (blockIdx.x - 256) * 512 + tt;
        if (gid >= 528384) return;
        float val;
        if (gid < 524288) {
            int r = gid >> 18;        // row 0/1 of edge_index_out
            int rem = gid & 262143;
            int b = rem >> 12;        // graph
            int p = rem & 4095;       // pair index within graph
            int v = (r == 0) ? (p >> 6) : (p & 63);
            val = (float)(v + b * 64);
        } else {
            val = (float)((gid - 524288) >> 6);   // batch_out
        }
        outp[524288 + gid] = t15_rb(val);
        return;
    }
    int lane = tt & 63;
    int wv = tt >> 6;              // 0..7
    int mt = wv & 3;               // k-tile
    int nt = wv >> 2;              // c-tile within quarter
    int rl = lane & 15, g2 = lane >> 4;
    int g = blockIdx.x >> 2;
    int cq = (blockIdx.x & 3) * 32;

    f32x4 acc = {0.f, 0.f, 0.f, 0.f};

    for (int tile = 0; tile < 8; ++tile) {
        size_t nbase = (size_t)g * NPER + tile * 128;
        if (tile) __syncthreads();
        // ---- stage S[128n][64k] bf16 -> St[64k][128n] fp16 (swizzled) ----
        const uint2* sg = (const uint2*)(S_in + nbase * KK);
        for (int i = 0; i < 4; ++i) {
            int idx = tt + 512 * i;          // 0..2047
            int r = idx >> 4;                // n
            int q = idx & 15;                // k quad
            uint2 u = sg[idx];
            unsigned short b[4] = {(unsigned short)(u.x & 0xffff),
                                   (unsigned short)(u.x >> 16),
                                   (unsigned short)(u.y & 0xffff),
                                   (unsigned short)(u.y >> 16)};
#pragma unroll
            for (int j = 0; j < 4; ++j) {
                int k = 4 * q + j;
                _Float16 h = (_Float16)t15_bf(b[j]);
                *(_Float16*)(sP + k * 256 + ((2 * r) ^ ((k & 7) << 4))) = h;
            }
        }
        // ---- stage X[128n][32c] f32 -> Xt[32c][128n] fp16 (swizzled) ----
        const float* xb = x + nbase * CC + cq;
        for (int i = 0; i < 2; ++i) {
            int idx = tt + 512 * i;          // 0..1023
            int r = idx >> 3;                // n
            int q = idx & 7;                 // c quad
            float4 v = *(const float4*)(xb + (size_t)r * CC + 4 * q);
#pragma unroll
            for (int j = 0; j < 4; ++j) {
                int c = 4 * q + j;
                float fv = (j == 0) ? v.x : (j == 1) ? v.y : (j == 2) ? v.z : v.w;
                _Float16 h = (_Float16)fv;
                *(_Float16*)(sP + 16384 + c * 256 + ((2 * r) ^ ((c & 7) << 4))) = h;
            }
        }
        __syncthreads();
        // ---- 4 K-steps of 32 n ----
#pragma unroll
        for (int ks = 0; ks < 4; ++ks) {
            int nb2 = 2 * (32 * ks + 8 * g2);          // byte offset of n-chunk
            int arow = 16 * mt + rl;
            uint4 ua = *(const uint4*)(sP + arow * 256 + (nb2 ^ ((arow & 7) << 4)));
            int brow = 16 * nt + rl;
            uint4 ub = *(const uint4*)(sP + 16384 + brow * 256 + (nb2 ^ ((brow & 7) << 4)));
            half8 A = __builtin_bit_cast(half8, ua);
            half8 B = __builtin_bit_cast(half8, ub);
            acc = __builtin_amdgcn_mfma_f32_16x16x32_f16(A, B, acc, 0, 0, 0);
        }
    }

    // ---- epilogue: C row = 4*g2 + reg (k within mt), col = rl (c within nt) ----
#pragma unroll
    for (int r = 0; r < 4; ++r) {
        int krow = 16 * mt + 4 * g2 + r;
        outp[(size_t)(g * KK + krow) * CC + cq + 16 * nt + rl] = t15_rb(acc[r]);
    }
}

// ---- Stage 5 (fallback only): edge_index_out + batch_out ----
__global__ void t15_edgefill(float* __restrict__ outp) {
    int gid = blockIdx.x * 256 + threadIdx.x;
    if (gid >= 528384) return;
    float val;
    if (gid < 524288) {
        int r = gid >> 18;        // row 0/1 of edge_index_out
        int rem = gid & 262143;
        int b = rem >> 12;        // graph
        int p = rem & 4095;       // pair index within graph
        int v = (r == 0) ? (p >> 6) : (p & 63);
        val = (float)(v + b * 64);
    } else {
        val = (float)((gid - 524288) >> 6);   // batch_out
    }
    outp[524288 + gid] = t15_rb(val);
}

extern "C" void kernel_launch(void* const* d_in, const int* in_sizes, int n_in,
                              void* d_out, int out_size, void* d_ws, size_t ws_size,
                              hipStream_t stream) {
    const float* x = nullptr; const int* ei = nullptr;
    const float* Wm = nullptr; const float* Wr = nullptr; const float* bias = nullptr;
    for (int i = 0; i < n_in; ++i) {
        int s = in_sizes[i];
        if (s == 8388608 && !x)       x  = (const float*)d_in[i];
        else if (s == 4194304 && !ei) ei = (const int*)d_in[i];
        else if (s == 8192) { if (!Wm) Wm = (const float*)d_in[i]; else if (!Wr) Wr = (const float*)d_in[i]; }
        else if (s == 64 && !bias)    bias = (const float*)d_in[i];
    }
    if (!x)  x  = (const float*)d_in[0];
    if (!ei) ei = (const int*)d_in[1];
    if (!Wm && n_in > 3) Wm = (const float*)d_in[3];
    if (!Wr && n_in > 4) Wr = (const float*)d_in[4];

    float* outp = (float*)d_out;           // d_out is FLOAT32
    bool out_ok = (out_size >= 1052672);
    bool ws_ok  = (ws_size >= WS_NEED) && x && ei && Wm && Wr;
    bool wf_ok  = (ws_size >= WS_NEED2);

    if (out_ok && !ws_ok) {
        t15_edgefill<<<2064, 256, 0, stream>>>(outp);
    }
    if (out_ok && ws_ok) {
        char* ws = (char*)d_ws;
        bf16*           m_buf  = (bf16*)(ws + M_OFF);
        bf16*           rootS  = (bf16*)(ws + R_OFF);
        unsigned short* sorted = (unsigned short*)(ws + SORT_OFF);
        unsigned short* rowptr = (unsigned short*)(ws + RP_OFF);
        float*          zbias  = (float*)(ws + ZB_OFF);
        unsigned short* wf     = wf_ok ? (unsigned short*)(ws + WF_OFF) : nullptr;
        int*            ghist  = (int*)(ws + GH_OFF);   // aliases m_buf (pre-mroot)
        int*            gcur   = (int*)(ws + GC_OFF);   // aliases m_buf (pre-mroot)
        const float* bz = bias ? bias : zbias;

        t15_hist<<<257, 1024, 0, stream>>>(ei, ghist, Wm, Wr, wf);
        t15_scan<<<64, 1024, 0, stream>>>(ghist, gcur, rowptr, zbias);
        t15_scat<<<256, 1024, 0, stream>>>(ei, gcur, sorted);
        if (wf_ok)
            t15_mroot_mfma<<<512, 256, 0, stream>>>(x, wf, bz, m_buf, rootS);
        else
            t15_mroot<<<NTOT / 64, 256, 0, stream>>>(x, Wm, Wr, bz, m_buf, rootS);
        t15_gatherlds<<<512, 1024, 0, stream>>>(rowptr, sorted,
                                                (const unsigned short*)m_buf, rootS);
        t15_pool_mfma<<<1288, 512, 0, stream>>>(x, rootS, outp);
    }
}